// Round 4
// baseline (193.111 us; speedup 1.0000x reference)
//
#include <hip/hip_runtime.h>

typedef _Float16 h8 __attribute__((ext_vector_type(8)));
typedef _Float16 h4 __attribute__((ext_vector_type(4)));
typedef float    f4 __attribute__((ext_vector_type(4)));
typedef float    f16v __attribute__((ext_vector_type(16)));

// XOR-swizzled index into a 128x128 half array stored in 16B (8-half) units:
// element (row,col) lives at row*128 + ((col>>3)^(row&15))*8 + (col&7).
// Fragment reads (8 consecutive halfs, col base multiple of 8) are one b128;
// 32 consecutive rows at the same col hit each bank exactly 4x (balanced min).
__device__ __forceinline__ int sw(int row, int col) {
    return row * 128 + ((((col >> 3) ^ (row & 15)) << 3) | (col & 7));
}

__device__ __forceinline__ f16v zero16() {
    f16v z;
    for (int i = 0; i < 16; ++i) z[i] = 0.f;
    return z;
}

// ---- prep (single dispatch): Mt[f][e] = sum_d Wk[d][f]Wq[d][e]; Wv->f16; ck[f] = bq.Wk ----
__global__ void prep(const float* __restrict__ Wq, const float* __restrict__ Wk,
                     const float* __restrict__ Wv, const float* __restrict__ bq,
                     _Float16* __restrict__ Mt, _Float16* __restrict__ Wvh,
                     float* __restrict__ ck) {
    if (blockIdx.x < 64) {
        int idx = blockIdx.x * 256 + threadIdx.x;
        int e = idx & 127, f = idx >> 7;
        float acc = 0.f;
        for (int d = 0; d < 128; ++d) acc += Wk[d * 128 + f] * Wq[d * 128 + e];
        Mt[idx] = (_Float16)acc;
    } else {
        int t = threadIdx.x;
        for (int i = 0; i < 16; ++i) {
            int off = (t + i * 256) * 4;
            f4 f = *(const f4*)(Wv + off);
            h4 h = {(_Float16)f.x, (_Float16)f.y, (_Float16)f.z, (_Float16)f.w};
            *(h4*)(Wvh + off) = h;
        }
        if (t < 128) {
            float a = 0.f;
            for (int d = 0; d < 128; ++d) a += bq[d] * Wk[d * 128 + t];
            ck[t] = a;
        }
    }
}

// One persistent 512-thread block per CU; 4 windows each, register-prefetched.
// 32x32x16 f16 MFMA. Wave wv: b = wv&3 (row/w-block), h = wv>>2 (half index).
// A-frag: A[m=lane&31][k=(lane>>5)*8+j]; B-frag: B[k][n=lane&31];
// C/D: col=lane&31, row=(reg&3)+8*(reg>>2)+4*(lane>>5).
// __launch_bounds__(512, 1): effective 2 waves/EU (8 waves over 4 SIMDs) ->
// 256-VGPR cap. (512,2) was scaled to an effective 4 waves/EU -> 128-VGPR cap
// -> ~112 regs of persistent weight/prefetch state spilled to scratch, +124 MB
// HBM traffic (R3 counters). Occupancy is LDS-bound at 1 block/CU either way.
__global__ __launch_bounds__(512, 1) void attn(
    const float* __restrict__ x, const _Float16* __restrict__ Mt,
    const _Float16* __restrict__ Wvh, const float* __restrict__ ck,
    const float* __restrict__ bv, float* __restrict__ out) {
    __shared__ __attribute__((aligned(16))) _Float16 Xs[2][16384];  // X; cur reused as P
    __shared__ __attribute__((aligned(16))) _Float16 Ts[16384];     // T'[w][f]
    __shared__ __attribute__((aligned(16))) _Float16 Vs[16384];     // V^T: Vs[d][u]
    __shared__ __attribute__((aligned(16))) float ckL[128];
    __shared__ __attribute__((aligned(16))) float redM[2][128];
    __shared__ __attribute__((aligned(16))) float redS[2][128];

    const int tid  = threadIdx.x;
    const int wv   = tid >> 6;
    const int lane = tid & 63;
    const int l32  = lane & 31;
    const int half = lane >> 5;
    const int b    = wv & 3;   // X row-block == w-block
    const int h    = wv >> 2;  // f/d/u half selector

    if (tid < 128) ckL[tid] = ck[tid];

    // persistent weight fragments: Mt rows (A for T'), Wv rows (B for V) -- 128 VGPR
    h8 mtA[2][8], wvB[2][8];
    for (int fi = 0; fi < 2; ++fi) {
        int F = 2 * h + fi;
        for (int k0 = 0; k0 < 8; ++k0) {
            mtA[fi][k0] = *(const h8*)(Mt  + (F * 32 + l32) * 128 + k0 * 16 + half * 8);
            wvB[fi][k0] = *(const h8*)(Wvh + (F * 32 + l32) * 128 + k0 * 16 + half * 8);
        }
    }
    float bvv[2] = { bv[(2 * h + 0) * 32 + l32], bv[(2 * h + 1) * 32 + l32] };

    const size_t base0 = (size_t)blockIdx.x * 4 * 16384;
    f4 pf[8];
    for (int j = 0; j < 8; ++j)
        pf[j] = *(const f4*)(x + base0 + 4 * tid + 2048 * j);

    for (int it = 0; it < 4; ++it) {
        _Float16* X = Xs[it & 1];

        // ---- stage prefetched regs -> swizzled f16 LDS ----
        for (int j = 0; j < 8; ++j) {
            int idx = 4 * tid + 2048 * j;
            int row = idx >> 7, col = idx & 127;
            f4 f = pf[j];
            h4 hv = {(_Float16)f.x, (_Float16)f.y, (_Float16)f.z, (_Float16)f.w};
            *(h4*)(&X[sw(row, col)]) = hv;
        }
        __syncthreads();  // A: X ready

        if (it < 3) {
            const float* nx = x + base0 + (size_t)(it + 1) * 16384;
            for (int j = 0; j < 8; ++j)
                pf[j] = *(const f4*)(nx + 4 * tid + 2048 * j);
        }

        const int xr = b * 32 + l32;  // this wave's X row for fragments

        // ---- phase 1a: T' tiles (rows f=2h+fi, cols w=b) = Mt x X^T ----
        {
            f16v a0 = zero16(), a1 = zero16();
            for (int k0 = 0; k0 < 8; ++k0) {
                h8 xf = *(const h8*)(&X[xr * 128 + (((k0 * 2 + half) ^ (xr & 15)) << 3)]);
                a0 = __builtin_amdgcn_mfma_f32_32x32x16_f16(mtA[0][k0], xf, a0, 0, 0, 0);
                a1 = __builtin_amdgcn_mfma_f32_32x32x16_f16(mtA[1][k0], xf, a1, 0, 0, 0);
            }
            int w = xr;  // C/D col = w
            for (int fi = 0; fi < 2; ++fi) {
                int F = 2 * h + fi;
                f16v a = fi ? a1 : a0;
                for (int q = 0; q < 4; ++q) {
                    f4 cb = *(const f4*)(&ckL[F * 32 + q * 8 + 4 * half]);
                    h4 hv = {(_Float16)(a[4 * q + 0] + cb.x), (_Float16)(a[4 * q + 1] + cb.y),
                             (_Float16)(a[4 * q + 2] + cb.z), (_Float16)(a[4 * q + 3] + cb.w)};
                    *(h4*)(&Ts[w * 128 + (((F * 4 + q) ^ (w & 15)) << 3) + 4 * half]) = hv;
                }
            }
        }
        // ---- phase 1b: V tiles (rows u=b, cols d=2h+di) = X x Wv^T; store Vs[d][u] ----
        {
            f16v a0 = zero16(), a1 = zero16();
            for (int k0 = 0; k0 < 8; ++k0) {
                h8 xf = *(const h8*)(&X[xr * 128 + (((k0 * 2 + half) ^ (xr & 15)) << 3)]);
                a0 = __builtin_amdgcn_mfma_f32_32x32x16_f16(xf, wvB[0][k0], a0, 0, 0, 0);
                a1 = __builtin_amdgcn_mfma_f32_32x32x16_f16(xf, wvB[1][k0], a1, 0, 0, 0);
            }
            for (int di = 0; di < 2; ++di) {
                int d = (2 * h + di) * 32 + l32;  // C/D col = d
                f16v a = di ? a1 : a0;
                for (int q = 0; q < 4; ++q) {
                    h4 hv = {(_Float16)(a[4 * q + 0] + bvv[di]), (_Float16)(a[4 * q + 1] + bvv[di]),
                             (_Float16)(a[4 * q + 2] + bvv[di]), (_Float16)(a[4 * q + 3] + bvv[di])};
                    *(h4*)(&Vs[d * 128 + (((b * 4 + q) ^ (d & 15)) << 3) + 4 * half]) = hv;
                }
            }
        }
        __syncthreads();  // B: Ts, Vs ready

        // ---- phase 2: S^T tiles (rows u=2h+t, cols w=b) = X x T'^T ----
        f16v s0 = zero16(), s1 = zero16();
        {
            int r0 = (2 * h + 0) * 32 + l32, r1 = (2 * h + 1) * 32 + l32;
            for (int k0 = 0; k0 < 8; ++k0) {
                h8 tf = *(const h8*)(&Ts[xr * 128 + (((k0 * 2 + half) ^ (xr & 15)) << 3)]);
                h8 x0 = *(const h8*)(&X[r0 * 128 + (((k0 * 2 + half) ^ (r0 & 15)) << 3)]);
                h8 x1 = *(const h8*)(&X[r1 * 128 + (((k0 * 2 + half) ^ (r1 & 15)) << 3)]);
                s0 = __builtin_amdgcn_mfma_f32_32x32x16_f16(x0, tf, s0, 0, 0, 0);
                s1 = __builtin_amdgcn_mfma_f32_32x32x16_f16(x1, tf, s1, 0, 0, 0);
            }
        }
        // wave-local max (this wave's 64 u's for column w), publish, cross-wave via LDS
        {
            float m = s0[0];
            for (int r = 1; r < 16; ++r) m = fmaxf(m, s0[r]);
            for (int r = 0; r < 16; ++r) m = fmaxf(m, s1[r]);
            m = fmaxf(m, __shfl_xor(m, 32, 64));
            if (lane < 32) redM[h][b * 32 + lane] = m;
        }
        __syncthreads();  // C1: maxes ready; all X readers done -> X reusable as P

        const int w = b * 32 + l32;
        {
            float M = fmaxf(redM[0][w], redM[1][w]);
            float sum = 0.f;
            _Float16* Ps = X;  // reuse current X buffer for P
            for (int t = 0; t < 2; ++t) {
                f16v s = t ? s1 : s0;
                int mb = 2 * h + t;
                for (int q = 0; q < 4; ++q) {
                    float e0 = __expf(s[4 * q + 0] - M), e1 = __expf(s[4 * q + 1] - M);
                    float e2 = __expf(s[4 * q + 2] - M), e3 = __expf(s[4 * q + 3] - M);
                    sum += e0 + e1 + e2 + e3;
                    h4 hv = {(_Float16)e0, (_Float16)e1, (_Float16)e2, (_Float16)e3};
                    *(h4*)(&Ps[w * 128 + (((mb * 4 + q) ^ (w & 15)) << 3) + 4 * half]) = hv;
                }
            }
            sum += __shfl_xor(sum, 32, 64);
            if (lane < 32) redS[h][b * 32 + lane] = sum;
        }
        __syncthreads();  // C2: P (unnormalized) + sums ready

        // ---- phase 3: O tiles (rows w=b, cols d=2h+di) = P x V ----
        f16v o0 = zero16(), o1 = zero16();
        {
            const _Float16* Ps = X;
            int d0r = (2 * h + 0) * 32 + l32, d1r = (2 * h + 1) * 32 + l32;
            for (int k0 = 0; k0 < 8; ++k0) {
                h8 pfr = *(const h8*)(&Ps[w * 128 + (((k0 * 2 + half) ^ (w & 15)) << 3)]);
                h8 v0 = *(const h8*)(&Vs[d0r * 128 + (((k0 * 2 + half) ^ (d0r & 15)) << 3)]);
                h8 v1 = *(const h8*)(&Vs[d1r * 128 + (((k0 * 2 + half) ^ (d1r & 15)) << 3)]);
                o0 = __builtin_amdgcn_mfma_f32_32x32x16_f16(pfr, v0, o0, 0, 0, 0);
                o1 = __builtin_amdgcn_mfma_f32_32x32x16_f16(pfr, v1, o1, 0, 0, 0);
            }
        }
        // epilogue: row w' gets scale 1/Z; 128B-coalesced dword stores
        float* ob = out + base0 + (size_t)it * 16384;
        for (int q = 0; q < 4; ++q) {
            int wr = b * 32 + q * 8 + 4 * half;
            f4 z0 = *(const f4*)(&redS[0][wr]);
            f4 z1 = *(const f4*)(&redS[1][wr]);
            f4 inv = {1.f / (z0.x + z1.x), 1.f / (z0.y + z1.y),
                      1.f / (z0.z + z1.z), 1.f / (z0.w + z1.w)};
            for (int di = 0; di < 2; ++di) {
                f16v a = di ? o1 : o0;
                int d = (2 * h + di) * 32 + l32;
                ob[(size_t)(wr + 0) * 128 + d] = a[4 * q + 0] * inv.x;
                ob[(size_t)(wr + 1) * 128 + d] = a[4 * q + 1] * inv.y;
                ob[(size_t)(wr + 2) * 128 + d] = a[4 * q + 2] * inv.z;
                ob[(size_t)(wr + 3) * 128 + d] = a[4 * q + 3] * inv.w;
            }
        }
    }
}

extern "C" void kernel_launch(void* const* d_in, const int* in_sizes, int n_in,
                              void* d_out, int out_size, void* d_ws, size_t ws_size,
                              hipStream_t stream) {
    const float* x  = (const float*)d_in[0];
    const float* Wq = (const float*)d_in[1];
    const float* bq = (const float*)d_in[2];
    const float* Wk = (const float*)d_in[3];
    // bk (d_in[4]) cancels in softmax
    const float* Wv = (const float*)d_in[5];
    const float* bv = (const float*)d_in[6];

    _Float16* Mt  = (_Float16*)d_ws;        // 32 KiB
    _Float16* Wvh = Mt + 16384;             // 32 KiB
    float*    ckp = (float*)(Wvh + 16384);  // 512 B

    prep<<<65, 256, 0, stream>>>(Wq, Wk, Wv, bq, Mt, Wvh, ckp);
    attn<<<256, 512, 0, stream>>>(x, Mt, Wvh, ckp, bv, (float*)d_out);
}

// Round 5
// 145.894 us; speedup vs baseline: 1.3236x; 1.3236x over previous
//
#include <hip/hip_runtime.h>

typedef _Float16 h8 __attribute__((ext_vector_type(8)));
typedef _Float16 h4 __attribute__((ext_vector_type(4)));
typedef float    f4 __attribute__((ext_vector_type(4)));
typedef float    f16v __attribute__((ext_vector_type(16)));

// XOR-swizzled index into a 128x128 half array stored in 16B (8-half) units:
// element (row,col) lives at row*128 + ((col>>3)^(row&15))*8 + (col&7).
// Fragment reads (8 consecutive halfs) are one b128; 32 consecutive rows at
// one col-unit hit each bank exactly 4x (balanced minimum for wave64).
__device__ __forceinline__ int sw(int row, int col) {
    return row * 128 + ((((col >> 3) ^ (row & 15)) << 3) | (col & 7));
}

__device__ __forceinline__ f16v zero16() {
    f16v z;
    for (int i = 0; i < 16; ++i) z[i] = 0.f;
    return z;
}

// ---- prep: Mt[f][e] = sum_d Wk[d][f]Wq[d][e] (f16); Wv->f16; ck[f] = bq.Wk ----
__global__ void prep(const float* __restrict__ Wq, const float* __restrict__ Wk,
                     const float* __restrict__ Wv, const float* __restrict__ bq,
                     _Float16* __restrict__ Mt, _Float16* __restrict__ Wvh,
                     float* __restrict__ ck) {
    if (blockIdx.x < 64) {
        int idx = blockIdx.x * 256 + threadIdx.x;
        int e = idx & 127, f = idx >> 7;
        float acc = 0.f;
        for (int d = 0; d < 128; ++d) acc += Wk[d * 128 + f] * Wq[d * 128 + e];
        Mt[idx] = (_Float16)acc;
    } else {
        int t = threadIdx.x;
        for (int i = 0; i < 16; ++i) {
            int off = (t + i * 256) * 4;
            f4 f = *(const f4*)(Wv + off);
            h4 h = {(_Float16)f.x, (_Float16)f.y, (_Float16)f.z, (_Float16)f.w};
            *(h4*)(Wvh + off) = h;
        }
        if (t < 128) {
            float a = 0.f;
            for (int d = 0; d < 128; ++d) a += bq[d] * Wk[d * 128 + t];
            ck[t] = a;
        }
    }
}

// One persistent 512-thread block per CU; 4 windows, register-prefetched (f16).
// 32x32x16 f16 MFMA. Phase-1 tiling: wave -> (F = wv&3 weight row-block,
// WP = wv>>2 -> column blocks {2WP, 2WP+1}). Only Mt fragments (32 VGPR) are
// persistent; Wv fragments are re-loaded from L1/L2 per window (transient).
// Phases 2/3 tiling: b = wv&3 (w-block), h = wv>>2 (u/d half), as before.
// Arch-VGPR peak ~110 < the 128 partition the backend picks for this kernel
// (R3/R4: 160+ persistent regs spilled to scratch => +124 MB HBM traffic).
__global__ __launch_bounds__(512) void attn(
    const float* __restrict__ x, const _Float16* __restrict__ Mt,
    const _Float16* __restrict__ Wvh, const float* __restrict__ ck,
    const float* __restrict__ bv, float* __restrict__ out) {
    __shared__ __attribute__((aligned(16))) _Float16 Xs[2][16384];  // X; cur reused as P
    __shared__ __attribute__((aligned(16))) _Float16 Ts[16384];     // T'[w][f]
    __shared__ __attribute__((aligned(16))) _Float16 Vs[16384];     // V^T: Vs[d][u]
    __shared__ __attribute__((aligned(16))) float ckL[128];
    __shared__ __attribute__((aligned(16))) float redM[2][128];
    __shared__ __attribute__((aligned(16))) float redS[2][128];

    const int tid  = threadIdx.x;
    const int wv   = tid >> 6;
    const int lane = tid & 63;
    const int l32  = lane & 31;
    const int half = lane >> 5;
    const int F    = wv & 3;   // phase-1 weight row-block
    const int WP   = wv >> 2;  // phase-1 column-block pair
    const int b    = wv & 3;   // phase-2/3 w-block
    const int h    = wv >> 2;  // phase-2/3 u/d half

    if (tid < 128) ckL[tid] = ck[tid];

    // persistent: Mt A-fragments for row-block F (32 VGPR)
    h8 mtA[8];
    for (int k0 = 0; k0 < 8; ++k0)
        mtA[k0] = *(const h8*)(Mt + (F * 32 + l32) * 128 + k0 * 16 + half * 8);
    const float bvv = bv[F * 32 + l32];

    const size_t base0 = (size_t)blockIdx.x * 4 * 16384;

    // prefetch window 0, converting to f16 immediately (16 VGPR held)
    h4 pf[8];
    for (int j = 0; j < 8; ++j) {
        f4 t = *(const f4*)(x + base0 + 4 * tid + 2048 * j);
        pf[j] = (h4){(_Float16)t.x, (_Float16)t.y, (_Float16)t.z, (_Float16)t.w};
    }

    for (int it = 0; it < 4; ++it) {
        _Float16* X = Xs[it & 1];

        // ---- stage prefetched f16 regs -> swizzled LDS ----
        for (int j = 0; j < 8; ++j) {
            int idx = 4 * tid + 2048 * j;
            *(h4*)(&X[sw(idx >> 7, idx & 127)]) = pf[j];
        }
        __syncthreads();  // A: X ready

        if (it < 3) {
            const float* nx = x + base0 + (size_t)(it + 1) * 16384;
            for (int j = 0; j < 8; ++j) {
                f4 t = *(const f4*)(nx + 4 * tid + 2048 * j);
                pf[j] = (h4){(_Float16)t.x, (_Float16)t.y, (_Float16)t.z, (_Float16)t.w};
            }
        }

        const int r0 = (2 * WP + 0) * 32 + l32;  // phase-1 column-block rows in X
        const int r1 = (2 * WP + 1) * 32 + l32;

        // ---- phase 1a: T' tiles (row-block F, col-blocks 2WP,2WP+1) = Mt x X^T ----
        {
            f16v a0 = zero16(), a1 = zero16();
            for (int k0 = 0; k0 < 8; ++k0) {
                h8 x0 = *(const h8*)(&X[r0 * 128 + (((k0 * 2 + half) ^ (r0 & 15)) << 3)]);
                h8 x1 = *(const h8*)(&X[r1 * 128 + (((k0 * 2 + half) ^ (r1 & 15)) << 3)]);
                a0 = __builtin_amdgcn_mfma_f32_32x32x16_f16(mtA[k0], x0, a0, 0, 0, 0);
                a1 = __builtin_amdgcn_mfma_f32_32x32x16_f16(mtA[k0], x1, a1, 0, 0, 0);
            }
            for (int wi = 0; wi < 2; ++wi) {
                int w = (2 * WP + wi) * 32 + l32;  // C/D col = w
                f16v a = wi ? a1 : a0;
                for (int q = 0; q < 4; ++q) {
                    f4 cb = *(const f4*)(&ckL[F * 32 + q * 8 + 4 * half]);
                    h4 hv = {(_Float16)(a[4 * q + 0] + cb.x), (_Float16)(a[4 * q + 1] + cb.y),
                             (_Float16)(a[4 * q + 2] + cb.z), (_Float16)(a[4 * q + 3] + cb.w)};
                    *(h4*)(&Ts[w * 128 + (((F * 4 + q) ^ (w & 15)) << 3) + 4 * half]) = hv;
                }
            }
        }
        // ---- phase 1b: V tiles (u-blocks 2WP,2WP+1, col-block F) = X x Wv^T ----
        {
            f16v a0 = zero16(), a1 = zero16();
            for (int k0 = 0; k0 < 8; ++k0) {
                // transient Wv B-fragment from global (L1/L2-resident after iter 0)
                h8 wB = *(const h8*)(Wvh + (F * 32 + l32) * 128 + k0 * 16 + half * 8);
                h8 x0 = *(const h8*)(&X[r0 * 128 + (((k0 * 2 + half) ^ (r0 & 15)) << 3)]);
                h8 x1 = *(const h8*)(&X[r1 * 128 + (((k0 * 2 + half) ^ (r1 & 15)) << 3)]);
                a0 = __builtin_amdgcn_mfma_f32_32x32x16_f16(x0, wB, a0, 0, 0, 0);
                a1 = __builtin_amdgcn_mfma_f32_32x32x16_f16(x1, wB, a1, 0, 0, 0);
            }
            int d = F * 32 + l32;  // C/D col = d
            for (int ui = 0; ui < 2; ++ui) {
                int ub = 2 * WP + ui;
                f16v a = ui ? a1 : a0;
                for (int q = 0; q < 4; ++q) {
                    h4 hv = {(_Float16)(a[4 * q + 0] + bvv), (_Float16)(a[4 * q + 1] + bvv),
                             (_Float16)(a[4 * q + 2] + bvv), (_Float16)(a[4 * q + 3] + bvv)};
                    *(h4*)(&Vs[d * 128 + (((ub * 4 + q) ^ (d & 15)) << 3) + 4 * half]) = hv;
                }
            }
        }
        __syncthreads();  // B: Ts, Vs ready

        const int xr = b * 32 + l32;  // phase-2/3 w-strip row

        // ---- phase 2: S^T tiles (u-blocks 2h,2h+1, w-block b) = X x T'^T ----
        f16v s0 = zero16(), s1 = zero16();
        {
            int u0 = (2 * h + 0) * 32 + l32, u1 = (2 * h + 1) * 32 + l32;
            for (int k0 = 0; k0 < 8; ++k0) {
                h8 tf = *(const h8*)(&Ts[xr * 128 + (((k0 * 2 + half) ^ (xr & 15)) << 3)]);
                h8 x0 = *(const h8*)(&X[u0 * 128 + (((k0 * 2 + half) ^ (u0 & 15)) << 3)]);
                h8 x1 = *(const h8*)(&X[u1 * 128 + (((k0 * 2 + half) ^ (u1 & 15)) << 3)]);
                s0 = __builtin_amdgcn_mfma_f32_32x32x16_f16(x0, tf, s0, 0, 0, 0);
                s1 = __builtin_amdgcn_mfma_f32_32x32x16_f16(x1, tf, s1, 0, 0, 0);
            }
        }
        // wave-local max over this wave's 64 u's per column w, publish
        {
            float m = s0[0];
            for (int r = 1; r < 16; ++r) m = fmaxf(m, s0[r]);
            for (int r = 0; r < 16; ++r) m = fmaxf(m, s1[r]);
            m = fmaxf(m, __shfl_xor(m, 32, 64));
            if (lane < 32) redM[h][b * 32 + lane] = m;
        }
        __syncthreads();  // C1: maxes ready; X readers done -> X reusable as P

        const int w = xr;
        {
            float M = fmaxf(redM[0][w], redM[1][w]);
            float sum = 0.f;
            _Float16* Ps = X;  // reuse current X buffer for P
            for (int t = 0; t < 2; ++t) {
                f16v s = t ? s1 : s0;
                int mb = 2 * h + t;
                for (int q = 0; q < 4; ++q) {
                    float e0 = __expf(s[4 * q + 0] - M), e1 = __expf(s[4 * q + 1] - M);
                    float e2 = __expf(s[4 * q + 2] - M), e3 = __expf(s[4 * q + 3] - M);
                    sum += e0 + e1 + e2 + e3;
                    h4 hv = {(_Float16)e0, (_Float16)e1, (_Float16)e2, (_Float16)e3};
                    *(h4*)(&Ps[w * 128 + (((mb * 4 + q) ^ (w & 15)) << 3) + 4 * half]) = hv;
                }
            }
            sum += __shfl_xor(sum, 32, 64);
            if (lane < 32) redS[h][b * 32 + lane] = sum;
        }
        __syncthreads();  // C2: P (unnormalized) + sums ready

        // ---- phase 3: O tiles (w-block b, d-blocks 2h,2h+1) = P x V ----
        f16v o0 = zero16(), o1 = zero16();
        {
            const _Float16* Ps = X;
            int d0 = (2 * h + 0) * 32 + l32, d1 = (2 * h + 1) * 32 + l32;
            for (int k0 = 0; k0 < 8; ++k0) {
                h8 pfr = *(const h8*)(&Ps[w * 128 + (((k0 * 2 + half) ^ (w & 15)) << 3)]);
                h8 v0 = *(const h8*)(&Vs[d0 * 128 + (((k0 * 2 + half) ^ (d0 & 15)) << 3)]);
                h8 v1 = *(const h8*)(&Vs[d1 * 128 + (((k0 * 2 + half) ^ (d1 & 15)) << 3)]);
                o0 = __builtin_amdgcn_mfma_f32_32x32x16_f16(pfr, v0, o0, 0, 0, 0);
                o1 = __builtin_amdgcn_mfma_f32_32x32x16_f16(pfr, v1, o1, 0, 0, 0);
            }
        }
        // epilogue: scale rows by 1/Z; 128B-run coalesced dword stores
        float* ob = out + base0 + (size_t)it * 16384;
        for (int q = 0; q < 4; ++q) {
            int wr = b * 32 + q * 8 + 4 * half;
            f4 z0 = *(const f4*)(&redS[0][wr]);
            f4 z1 = *(const f4*)(&redS[1][wr]);
            f4 inv = {1.f / (z0.x + z1.x), 1.f / (z0.y + z1.y),
                      1.f / (z0.z + z1.z), 1.f / (z0.w + z1.w)};
            for (int di = 0; di < 2; ++di) {
                f16v a = di ? o1 : o0;
                int d = (2 * h + di) * 32 + l32;
                ob[(size_t)(wr + 0) * 128 + d] = a[4 * q + 0] * inv.x;
                ob[(size_t)(wr + 1) * 128 + d] = a[4 * q + 1] * inv.y;
                ob[(size_t)(wr + 2) * 128 + d] = a[4 * q + 2] * inv.z;
                ob[(size_t)(wr + 3) * 128 + d] = a[4 * q + 3] * inv.w;
            }
        }
    }
}

extern "C" void kernel_launch(void* const* d_in, const int* in_sizes, int n_in,
                              void* d_out, int out_size, void* d_ws, size_t ws_size,
                              hipStream_t stream) {
    const float* x  = (const float*)d_in[0];
    const float* Wq = (const float*)d_in[1];
    const float* bq = (const float*)d_in[2];
    const float* Wk = (const float*)d_in[3];
    // bk (d_in[4]) cancels in softmax
    const float* Wv = (const float*)d_in[5];
    const float* bv = (const float*)d_in[6];

    _Float16* Mt  = (_Float16*)d_ws;        // 32 KiB
    _Float16* Wvh = Mt + 16384;             // 32 KiB
    float*    ckp = (float*)(Wvh + 16384);  // 512 B

    prep<<<65, 256, 0, stream>>>(Wq, Wk, Wv, bq, Mt, Wvh, ckp);
    attn<<<256, 512, 0, stream>>>(x, Mt, Wvh, ckp, bv, (float*)d_out);
}